// Round 5
// baseline (427.240 us; speedup 1.0000x reference)
//
#include <hip/hip_runtime.h>
#include <hip/hip_bf16.h>

// out[8192,4096] fp32 = x[8192,4096] fp32 @ W[4096,4096] (int8 in int32 container)
// Path: fused prep (per-row int8 quantize x || W transpose) -> i8 MFMA GEMM
// (128x128 tile, BK=128, 256 threads, 64 KiB LDS -> 2 blocks/CU, 4-phase counted-vmcnt
// pipeline, XOR-swizzled LDS, XCD-swizzled grid, LDS-staged coalesced epilogue).
#define M_DIM 8192
#define N_DIM 4096
#define K_DIM 4096

typedef __attribute__((ext_vector_type(4))) int int4v;
typedef __attribute__((ext_vector_type(8))) short short8;
typedef __attribute__((ext_vector_type(4))) float floatx4;

__device__ __forceinline__ unsigned short f2bf(float f) {
    union { float f; unsigned int u; } cv; cv.f = f;
    unsigned int u = cv.u;
    return (unsigned short)((u + 0x7fffu + ((u >> 16) & 1u)) >> 16);
}

// ---------------- fused pre-pass: blocks [0,8192) quantize x rows; [8192,12288) transpose W ----------------
__global__ __launch_bounds__(256) void prep_kernel(const float* __restrict__ X,
                                                   const int* __restrict__ W,
                                                   char* __restrict__ Xq,
                                                   float* __restrict__ scales,
                                                   char* __restrict__ WT) {
    __shared__ float wmax[4];
    __shared__ int trans[64][17];
    const int t = threadIdx.x;

    if (blockIdx.x < M_DIM) {
        // ---- xq: one row per block ----
        const int row = blockIdx.x;
        const float4* src = (const float4*)(X + (size_t)row * K_DIM);
        float4 v[4];
        float am = 0.f;
#pragma unroll
        for (int i = 0; i < 4; ++i) {
            v[i] = src[t + i * 256];
            am = fmaxf(am, fmaxf(fmaxf(fabsf(v[i].x), fabsf(v[i].y)),
                                 fmaxf(fabsf(v[i].z), fabsf(v[i].w))));
        }
#pragma unroll
        for (int off = 32; off; off >>= 1) am = fmaxf(am, __shfl_xor(am, off, 64));
        if ((t & 63) == 0) wmax[t >> 6] = am;
        __syncthreads();
        am = fmaxf(fmaxf(wmax[0], wmax[1]), fmaxf(wmax[2], wmax[3]));
        am = fmaxf(am, 1e-20f);
        const float inv = 127.f / am;
        unsigned int* dst = (unsigned int*)(Xq + (size_t)row * K_DIM);
#pragma unroll
        for (int i = 0; i < 4; ++i) {
            int q0 = __float2int_rn(v[i].x * inv);
            int q1 = __float2int_rn(v[i].y * inv);
            int q2 = __float2int_rn(v[i].z * inv);
            int q3 = __float2int_rn(v[i].w * inv);
            dst[t + i * 256] = (unsigned int)(q0 & 255) | ((unsigned int)(q1 & 255) << 8) |
                               ((unsigned int)(q2 & 255) << 16) | ((unsigned int)q3 << 24);
        }
        if (t == 0) scales[row] = am * (1.f / 127.f);
    } else {
        // ---- wq: 64x64 tile transpose, W[K][N] int32 -> WT[N][K] int8 ----
        const int b  = blockIdx.x - M_DIM;
        const int tn = b & 63;          // N/64 = 64
        const int tk = b >> 6;          // K/64 = 64
        const int n  = t & 63;
        const int kg = t >> 6;

#pragma unroll
        for (int p = 0; p < 4; ++p) {
            const int kb = p * 16 + kg * 4;
            const int* src = W + (size_t)(tk * 64 + kb) * N_DIM + tn * 64 + n;
            int v0 = src[0];
            int v1 = src[N_DIM];
            int v2 = src[2 * N_DIM];
            int v3 = src[3 * N_DIM];
            trans[n][kb >> 2] = (v0 & 255) | ((v1 & 255) << 8) | ((v2 & 255) << 16) |
                                ((unsigned int)v3 << 24);
        }
        __syncthreads();

        const int n2 = t >> 2;
        const int c  = t & 3;
        int o0 = trans[n2][c * 4 + 0];
        int o1 = trans[n2][c * 4 + 1];
        int o2 = trans[n2][c * 4 + 2];
        int o3 = trans[n2][c * 4 + 3];
        char* dst = WT + (size_t)(tn * 64 + n2) * K_DIM + tk * 64 + c * 16;
        int4 o; o.x = o0; o.y = o1; o.z = o2; o.w = o3;
        *(int4*)dst = o;
    }
}

// ---------------- main GEMM: 128x128 tile, BK=128, 4 waves, 4-phase pipeline, 2 blocks/CU ----------------
// LDS: A [2][128][128] at 0 (32 KiB), B [2][128][128] at 32768 (32 KiB) = 64 KiB total.
// Swizzle: 16B chunk slot s stores global chunk c = s ^ (row & 7) (involution).
// global_load_lds dest is linear (wave base + lane*16); source address carries the swizzle.
#define GLL(src, dst) __builtin_amdgcn_global_load_lds( \
    (const __attribute__((address_space(1))) void*)(src), \
    (__attribute__((address_space(3))) void*)(dst), 16, 0, 0)

__global__ __launch_bounds__(256, 2) void gemm_i8(const char* __restrict__ A,
                                                  const char* __restrict__ BT,
                                                  const float* __restrict__ scales,
                                                  float* __restrict__ C) {
    __shared__ __attribute__((aligned(16))) char lds[65536];

    const int t    = threadIdx.x;
    const int lane = t & 63;
    const int wave = t >> 6;

    // XCD-aware chunked swizzle (bijective: 2048 tiles, 2048 % 8 == 0, 256 per XCD).
    // XCD k gets 8 contiguous bm rows (all 32 bn) -> A-panel reuse is L2-local.
    const int lin = blockIdx.y * 32 + blockIdx.x;      // grid = (32, 64)
    const int wg  = ((lin & 7) << 8) + (lin >> 3);
    const int bn  = wg & 31;
    const int bm  = wg >> 5;

    const int waveM = (wave >> 1) * 64;   // 2 M-groups
    const int waveN = (wave & 1) * 64;    // 2 N-groups

    // staging: thread t -> row = t>>3 within a 32-row call, chunk slot = t&7.
    // Pre-swizzled source chunk so linear LDS write lands swizzled.
    const int srow = t >> 3;                     // 0..31
    const int schk = (t & 7) ^ (srow & 7);
    const char* aSrc = A  + (size_t)(bm * 128 + srow) * K_DIM + schk * 16;
    const char* bSrc = BT + (size_t)(bn * 128 + srow) * K_DIM + schk * 16;
    char* aDst = lds + wave * 1024;              // wave-uniform; HW adds lane*16
    char* bDst = lds + 32768 + wave * 1024;

    // one tile = 128 rows x 128 B = 16 KiB = 4 GLL calls (each 32 rows / 4 KiB)
#define STG_A(buf, kt) do { \
    GLL(aSrc + (size_t)0  * K_DIM + (kt) * 128, aDst + (buf) * 16384 + 0 * 128);  \
    GLL(aSrc + (size_t)32 * K_DIM + (kt) * 128, aDst + (buf) * 16384 + 32 * 128); \
    GLL(aSrc + (size_t)64 * K_DIM + (kt) * 128, aDst + (buf) * 16384 + 64 * 128); \
    GLL(aSrc + (size_t)96 * K_DIM + (kt) * 128, aDst + (buf) * 16384 + 96 * 128); \
} while (0)
#define STG_B(buf, kt) do { \
    GLL(bSrc + (size_t)0  * K_DIM + (kt) * 128, bDst + (buf) * 16384 + 0 * 128);  \
    GLL(bSrc + (size_t)32 * K_DIM + (kt) * 128, bDst + (buf) * 16384 + 32 * 128); \
    GLL(bSrc + (size_t)64 * K_DIM + (kt) * 128, bDst + (buf) * 16384 + 64 * 128); \
    GLL(bSrc + (size_t)96 * K_DIM + (kt) * 128, bDst + (buf) * 16384 + 96 * 128); \
} while (0)

    // fragment reads: row = waveBase + frag*16 + (lane&15), chunk = kk*4 + (lane>>4),
    // swizzled slot = chunk ^ (row&7) = chunk ^ (lane&7).
    const char* fA = lds + (waveM + (lane & 15)) * 128;
    const char* fB = lds + 32768 + (waveN + (lane & 15)) * 128;
    const int sw0 = (((lane >> 4) + 0) ^ (lane & 7)) * 16;   // kk = 0
    const int sw1 = (((lane >> 4) + 4) ^ (lane & 7)) * 16;   // kk = 1

    int4v acc[4][4];
#pragma unroll
    for (int i = 0; i < 4; ++i)
#pragma unroll
        for (int j = 0; j < 4; ++j) acc[i][j] = (int4v){0, 0, 0, 0};

    int4v a[4][2], b[4][2];

#define LDA(buf) do { \
    _Pragma("unroll") \
    for (int i2 = 0; i2 < 4; ++i2) { \
        a[i2][0] = *(const int4v*)(fA + (buf) * 16384 + i2 * 2048 + sw0); \
        a[i2][1] = *(const int4v*)(fA + (buf) * 16384 + i2 * 2048 + sw1); \
    } \
} while (0)
#define LDB(buf, j0) do { \
    _Pragma("unroll") \
    for (int j2 = 0; j2 < 2; ++j2) { \
        b[(j0) + j2][0] = *(const int4v*)(fB + (buf) * 16384 + ((j0) + j2) * 2048 + sw0); \
        b[(j0) + j2][1] = *(const int4v*)(fB + (buf) * 16384 + ((j0) + j2) * 2048 + sw1); \
    } \
} while (0)
#define MFMAQ(j0) do { \
    _Pragma("unroll") \
    for (int i2 = 0; i2 < 4; ++i2) \
    _Pragma("unroll") \
    for (int j2 = 0; j2 < 2; ++j2) { \
        acc[i2][(j0) + j2] = __builtin_amdgcn_mfma_i32_16x16x64_i8( \
            a[i2][0], b[(j0) + j2][0], acc[i2][(j0) + j2], 0, 0, 0); \
        acc[i2][(j0) + j2] = __builtin_amdgcn_mfma_i32_16x16x64_i8( \
            a[i2][1], b[(j0) + j2][1], acc[i2][(j0) + j2], 0, 0, 0); \
    } \
} while (0)

    // prologue: tile0 -> buf0 (8 calls; drained at first p0 vmcnt(8)).
    STG_A(0, 0); STG_B(0, 0);

    // 32 K-tiles of 128; 2 tiles per iteration (buf0 then buf1), 4 phases.
    // Staging: p0 stages tile kt+1 -> buf1 (8 calls), p2/p3 stage tile kt+2 -> buf0 (4+4).
    // Derived waits: p0 vmcnt(8) drains tile kt (staged prev p2/p3);
    //                p2 vmcnt(4) drains tile kt+1 (staged this p0). Never 0 mid-loop.
#pragma unroll 1
    for (int it = 0; it < 16; ++it) {
        const int kt = it * 2;
        const bool more = (it < 15);

        // ---- phase 0: tile-start buf0 (tile kt), j=0..1 ----
        STG_A(1, kt + 1);
        STG_B(1, kt + 1);
        asm volatile("s_waitcnt vmcnt(8)" ::: "memory");
        __builtin_amdgcn_s_barrier();
        LDA(0); LDB(0, 0);
        __builtin_amdgcn_s_setprio(1);
        MFMAQ(0);
        __builtin_amdgcn_s_setprio(0);
        __builtin_amdgcn_s_barrier();

        // ---- phase 1: buf0, j=2..3 ----
        LDB(0, 2);
        __builtin_amdgcn_s_barrier();
        __builtin_amdgcn_s_setprio(1);
        MFMAQ(2);
        __builtin_amdgcn_s_setprio(0);
        __builtin_amdgcn_s_barrier();

        // ---- phase 2: tile-start buf1 (tile kt+1), j=0..1 ----
        if (more) {
            STG_A(0, kt + 2);
            asm volatile("s_waitcnt vmcnt(4)" ::: "memory");
        } else {
            asm volatile("s_waitcnt vmcnt(0)" ::: "memory");
        }
        __builtin_amdgcn_s_barrier();
        LDA(1); LDB(1, 0);
        __builtin_amdgcn_s_setprio(1);
        MFMAQ(0);
        __builtin_amdgcn_s_setprio(0);
        __builtin_amdgcn_s_barrier();

        // ---- phase 3: buf1, j=2..3 ----
        if (more) STG_B(0, kt + 2);
        LDB(1, 2);
        __builtin_amdgcn_s_barrier();
        __builtin_amdgcn_s_setprio(1);
        MFMAQ(2);
        __builtin_amdgcn_s_setprio(0);
        __builtin_amdgcn_s_barrier();
    }

    // ---- epilogue: LDS-staged transpose -> coalesced dwordx4 C stores ----
    // lds[] is dead after the final barrier. Each wave owns a disjoint 16 KiB region
    // viewed as fp32[64][64], column-XOR-swizzled by ((row&7)<<2):
    //   write side (b32): 2-way bank aliasing = free; read side (b128): bijective.
    // No barriers needed: regions are per-wave; intra-wave ordering via lgkmcnt.
    {
        float* reg4 = (float*)(lds + wave * 16384);
        const int ec = lane & 15;
        const int er = (lane >> 4) << 2;
        const size_t growBase = (size_t)(bm * 128 + waveM);
        const size_t gcolBase = (size_t)(bn * 128 + waveN);
        // write phase: scaled fp32 into swizzled [64][64]
#pragma unroll
        for (int i2 = 0; i2 < 4; ++i2) {
            const int rbase = i2 * 16 + er;
            const float4 s4 = *(const float4*)(scales + growBase + rbase);
            const float sc4[4] = {s4.x, s4.y, s4.z, s4.w};
#pragma unroll
            for (int j = 0; j < 4; ++j) {
                const int col = j * 16 + ec;
#pragma unroll
                for (int rr = 0; rr < 4; ++rr) {
                    const int row = rbase + rr;
                    reg4[row * 64 + (col ^ ((row & 7) << 2))] =
                        (float)acc[i2][j][rr] * sc4[rr];
                }
            }
        }
        // read phase: per instruction 4 rows x 256B contiguous -> dwordx4 stores
        const int c4 = ec << 2;
#pragma unroll 4
        for (int q = 0; q < 16; ++q) {
            const int R = (lane >> 4) + q * 4;
            const floatx4 v = *(const floatx4*)&reg4[R * 64 + (c4 ^ ((R & 7) << 2))];
            float* dst = C + (growBase + R) * N_DIM + gcolBase + c4;
            __builtin_nontemporal_store(v, (floatx4*)dst);
        }
    }
}

// ---------------- fallback GEMM (no workspace): bf16, inline-converts x and W ----------------
__global__ __launch_bounds__(256) void gemm_fb(const float* __restrict__ X,
                                               const int* __restrict__ W,
                                               float* __restrict__ C) {
    __shared__ __attribute__((aligned(16))) unsigned short sA[128 * 32];
    __shared__ __attribute__((aligned(16))) unsigned short sB[128 * 32];

    const int t    = threadIdx.x;
    const int lane = t & 63;
    const int wave = t >> 6;
    const int bn   = blockIdx.x;
    const int bm   = blockIdx.y;
    const int waveM = (wave >> 1) * 64;
    const int waveN = (wave & 1) * 64;

    const int ar = t >> 1, ac = (t & 1) << 4;
    const float* gX = X + (size_t)(bm * 128 + ar) * K_DIM + ac;
    const int br = t >> 3, bc = (t & 7) << 4;
    const int* gW = W + (size_t)br * N_DIM + bn * 128 + bc;

    const int fr = lane & 15;
    const int fk = (lane >> 4) << 3;
    const unsigned short* fA = sA + (waveM + fr) * 32 + fk;
    const unsigned short* fB = sB + (waveN + fr) * 32 + fk;

    floatx4 acc[4][4];
#pragma unroll
    for (int i = 0; i < 4; ++i)
#pragma unroll
        for (int j = 0; j < 4; ++j) acc[i][j] = (floatx4){0.f, 0.f, 0.f, 0.f};

    for (int k0 = 0; k0 < K_DIM; k0 += 32) {
        {
            const float4* p = (const float4*)gX;
            float4 v0 = p[0], v1 = p[1], v2 = p[2], v3 = p[3];
            uint4 o0, o1;
            o0.x = (unsigned int)f2bf(v0.x) | ((unsigned int)f2bf(v0.y) << 16);
            o0.y = (unsigned int)f2bf(v0.z) | ((unsigned int)f2bf(v0.w) << 16);
            o0.z = (unsigned int)f2bf(v1.x) | ((unsigned int)f2bf(v1.y) << 16);
            o0.w = (unsigned int)f2bf(v1.z) | ((unsigned int)f2bf(v1.w) << 16);
            o1.x = (unsigned int)f2bf(v2.x) | ((unsigned int)f2bf(v2.y) << 16);
            o1.y = (unsigned int)f2bf(v2.z) | ((unsigned int)f2bf(v2.w) << 16);
            o1.z = (unsigned int)f2bf(v3.x) | ((unsigned int)f2bf(v3.y) << 16);
            o1.w = (unsigned int)f2bf(v3.z) | ((unsigned int)f2bf(v3.w) << 16);
            uint4* d = (uint4*)&sA[ar * 32 + ac];
            d[0] = o0; d[1] = o1;
        }
        {
#pragma unroll
            for (int q = 0; q < 4; ++q) {
                int4 v = ((const int4*)gW)[q];
                sB[(bc + q * 4 + 0) * 32 + br] = f2bf((float)v.x);
                sB[(bc + q * 4 + 1) * 32 + br] = f2bf((float)v.y);
                sB[(bc + q * 4 + 2) * 32 + br] = f2bf((float)v.z);
                sB[(bc + q * 4 + 3) * 32 + br] = f2bf((float)v.w);
            }
        }
        gX += 32;
        gW += (size_t)32 * N_DIM;
        __syncthreads();

        short8 a[4], b[4];
#pragma unroll
        for (int i = 0; i < 4; ++i) a[i] = *(const short8*)(fA + i * 16 * 32);
#pragma unroll
        for (int j = 0; j < 4; ++j) b[j] = *(const short8*)(fB + j * 16 * 32);
#pragma unroll
        for (int i = 0; i < 4; ++i)
#pragma unroll
            for (int j = 0; j < 4; ++j)
                acc[i][j] = __builtin_amdgcn_mfma_f32_16x16x32_bf16(a[i], b[j], acc[i][j], 0, 0, 0);
        __syncthreads();
    }

    const int er = (lane >> 4) << 2;
    const int ec = lane & 15;
#pragma unroll
    for (int i = 0; i < 4; ++i)
#pragma unroll
        for (int j = 0; j < 4; ++j) {
            const size_t row0 = (size_t)(bm * 128 + waveM + i * 16 + er);
            const size_t col  = (size_t)(bn * 128 + waveN + j * 16 + ec);
#pragma unroll
            for (int rr = 0; rr < 4; ++rr) C[(row0 + rr) * N_DIM + col] = acc[i][j][rr];
        }
}

extern "C" void kernel_launch(void* const* d_in, const int* in_sizes, int n_in,
                              void* d_out, int out_size, void* d_ws, size_t ws_size,
                              hipStream_t stream) {
    const float* x = (const float*)d_in[0];
    const int*   w = (const int*)d_in[1];
    float* out = (float*)d_out;

    const size_t bytesXq = (size_t)M_DIM * K_DIM;        // 32 MiB
    const size_t bytesWT = (size_t)K_DIM * N_DIM;        // 16 MiB
    const size_t bytesSc = (size_t)M_DIM * sizeof(float);

    if (ws_size >= bytesXq + bytesWT + bytesSc) {
        char*  Xq = (char*)d_ws;
        char*  WT = (char*)d_ws + bytesXq;
        float* Sc = (float*)((char*)d_ws + bytesXq + bytesWT);
        prep_kernel<<<M_DIM + (N_DIM / 64) * (K_DIM / 64), 256, 0, stream>>>(x, w, Xq, Sc, WT);
        gemm_i8<<<dim3(N_DIM / 128, M_DIM / 128), 256, 0, stream>>>(Xq, WT, Sc, out);
    } else {
        gemm_fb<<<dim3(N_DIM / 128, M_DIM / 128), 256, 0, stream>>>(x, w, out);
    }
}

// Round 6
// 385.695 us; speedup vs baseline: 1.1077x; 1.1077x over previous
//
#include <hip/hip_runtime.h>
#include <hip/hip_bf16.h>

// out[8192,4096] fp32 = x[8192,4096] fp32 @ W[4096,4096] (int8 in int32 container)
// Path: fused prep (per-row int8 quantize x || W transpose) -> i8 MFMA GEMM
// (256x256 tile, BK=128, 512 thr, 2-barrier-per-K-tile deep pipeline, counted vmcnt,
// XOR-swizzled LDS, XCD-swizzled grid, LDS-staged coalesced epilogue).
#define M_DIM 8192
#define N_DIM 4096
#define K_DIM 4096

typedef __attribute__((ext_vector_type(4))) int int4v;
typedef __attribute__((ext_vector_type(8))) short short8;
typedef __attribute__((ext_vector_type(4))) float floatx4;

__device__ __forceinline__ unsigned short f2bf(float f) {
    union { float f; unsigned int u; } cv; cv.f = f;
    unsigned int u = cv.u;
    return (unsigned short)((u + 0x7fffu + ((u >> 16) & 1u)) >> 16);
}

// ---------------- fused pre-pass: blocks [0,8192) quantize x rows; [8192,12288) transpose W ----------------
__global__ __launch_bounds__(256) void prep_kernel(const float* __restrict__ X,
                                                   const int* __restrict__ W,
                                                   char* __restrict__ Xq,
                                                   float* __restrict__ scales,
                                                   char* __restrict__ WT) {
    __shared__ float wmax[4];
    __shared__ int trans[64][17];
    const int t = threadIdx.x;

    if (blockIdx.x < M_DIM) {
        // ---- xq: one row per block ----
        const int row = blockIdx.x;
        const float4* src = (const float4*)(X + (size_t)row * K_DIM);
        float4 v[4];
        float am = 0.f;
#pragma unroll
        for (int i = 0; i < 4; ++i) {
            v[i] = src[t + i * 256];
            am = fmaxf(am, fmaxf(fmaxf(fabsf(v[i].x), fabsf(v[i].y)),
                                 fmaxf(fabsf(v[i].z), fabsf(v[i].w))));
        }
#pragma unroll
        for (int off = 32; off; off >>= 1) am = fmaxf(am, __shfl_xor(am, off, 64));
        if ((t & 63) == 0) wmax[t >> 6] = am;
        __syncthreads();
        am = fmaxf(fmaxf(wmax[0], wmax[1]), fmaxf(wmax[2], wmax[3]));
        am = fmaxf(am, 1e-20f);
        const float inv = 127.f / am;
        unsigned int* dst = (unsigned int*)(Xq + (size_t)row * K_DIM);
#pragma unroll
        for (int i = 0; i < 4; ++i) {
            int q0 = __float2int_rn(v[i].x * inv);
            int q1 = __float2int_rn(v[i].y * inv);
            int q2 = __float2int_rn(v[i].z * inv);
            int q3 = __float2int_rn(v[i].w * inv);
            dst[t + i * 256] = (unsigned int)(q0 & 255) | ((unsigned int)(q1 & 255) << 8) |
                               ((unsigned int)(q2 & 255) << 16) | ((unsigned int)q3 << 24);
        }
        if (t == 0) scales[row] = am * (1.f / 127.f);
    } else {
        // ---- wq: 64x64 tile transpose, W[K][N] int32 -> WT[N][K] int8 ----
        const int b  = blockIdx.x - M_DIM;
        const int tn = b & 63;          // N/64 = 64
        const int tk = b >> 6;          // K/64 = 64
        const int n  = t & 63;
        const int kg = t >> 6;

#pragma unroll
        for (int p = 0; p < 4; ++p) {
            const int kb = p * 16 + kg * 4;
            const int* src = W + (size_t)(tk * 64 + kb) * N_DIM + tn * 64 + n;
            int v0 = src[0];
            int v1 = src[N_DIM];
            int v2 = src[2 * N_DIM];
            int v3 = src[3 * N_DIM];
            trans[n][kb >> 2] = (v0 & 255) | ((v1 & 255) << 8) | ((v2 & 255) << 16) |
                                ((unsigned int)v3 << 24);
        }
        __syncthreads();

        const int n2 = t >> 2;
        const int c  = t & 3;
        int o0 = trans[n2][c * 4 + 0];
        int o1 = trans[n2][c * 4 + 1];
        int o2 = trans[n2][c * 4 + 2];
        int o3 = trans[n2][c * 4 + 3];
        char* dst = WT + (size_t)(tn * 64 + n2) * K_DIM + tk * 64 + c * 16;
        int4 o; o.x = o0; o.y = o1; o.z = o2; o.w = o3;
        *(int4*)dst = o;
    }
}

// ---------------- main GEMM: 256x256 tile, BK=128, 8 waves, 2 barriers per K-tile ----------------
// LDS: A [2][256][128] at 0 (64 KiB), B [2][256][128] at 65536 (64 KiB).
// Swizzle: 16B chunk slot s stores global chunk c = s ^ (row & 7) (involution).
// global_load_lds dest is linear (wave base + lane*16); source address carries the swizzle.
#define GLL(src, dst) __builtin_amdgcn_global_load_lds( \
    (const __attribute__((address_space(1))) void*)(src), \
    (__attribute__((address_space(3))) void*)(dst), 16, 0, 0)

__global__ __launch_bounds__(512, 2) void gemm_i8(const char* __restrict__ A,
                                                  const char* __restrict__ BT,
                                                  const float* __restrict__ scales,
                                                  float* __restrict__ C) {
    __shared__ __attribute__((aligned(16))) char lds[131072];

    const int t    = threadIdx.x;
    const int lane = t & 63;
    const int wave = t >> 6;

    // XCD-aware chunked swizzle (bijective: 512 tiles, 512 % 8 == 0, 64 per XCD).
    const int lin = blockIdx.y * 16 + blockIdx.x;      // grid = (16, 32)
    const int wg  = ((lin & 7) << 6) + (lin >> 3);
    const int bn  = wg & 15;
    const int bm  = wg >> 4;

    const int waveM = (wave >> 2) * 128;   // 2 M-groups
    const int waveN = (wave & 3) * 64;     // 4 N-groups

    // staging: thread t -> row = t>>3 within a 64-row call, chunk slot = t&7.
    // Pre-swizzled source chunk so linear LDS write lands swizzled.
    const int srow = t >> 3;                     // 0..63
    const int schk = (t & 7) ^ (srow & 7);
    const char* aSrc = A  + (size_t)(bm * 256 + srow) * K_DIM + schk * 16;
    const char* bSrc = BT + (size_t)(bn * 256 + srow) * K_DIM + schk * 16;
    char* aDst = lds + wave * 1024;              // wave-uniform; HW adds lane*16
    char* bDst = lds + 65536 + wave * 1024;

#define STG_A(buf, r0, kt) do { \
    GLL(aSrc + (size_t)(r0) * K_DIM + (kt) * 128,        aDst + (buf) * 32768 + (r0) * 128); \
    GLL(aSrc + (size_t)((r0) + 64) * K_DIM + (kt) * 128, aDst + (buf) * 32768 + ((r0) + 64) * 128); \
} while (0)
#define STG_B(buf, r0, kt) do { \
    GLL(bSrc + (size_t)(r0) * K_DIM + (kt) * 128,        bDst + (buf) * 32768 + (r0) * 128); \
    GLL(bSrc + (size_t)((r0) + 64) * K_DIM + (kt) * 128, bDst + (buf) * 32768 + ((r0) + 64) * 128); \
} while (0)
#define STG_TILE(buf, kt) do { \
    STG_A(buf, 0, kt); STG_A(buf, 128, kt); \
    STG_B(buf, 0, kt); STG_B(buf, 128, kt); \
} while (0)

    // fragment reads: row = waveBase + frag*16 + (lane&15), chunk = kk*4 + (lane>>4),
    // swizzled slot = chunk ^ (row&7) = chunk ^ (lane&7).
    const char* fA = lds + (waveM + (lane & 15)) * 128;
    const char* fB = lds + 65536 + (waveN + (lane & 15)) * 128;
    const int sw0 = (((lane >> 4) + 0) ^ (lane & 7)) * 16;   // kk = 0
    const int sw1 = (((lane >> 4) + 4) ^ (lane & 7)) * 16;   // kk = 1

    int4v acc[8][4];
#pragma unroll
    for (int i = 0; i < 8; ++i)
#pragma unroll
        for (int j = 0; j < 4; ++j) acc[i][j] = (int4v){0, 0, 0, 0};

    int4v a[4][2], b[4][2];

#define LDA(buf, mh) do { \
    _Pragma("unroll") \
    for (int i2 = 0; i2 < 4; ++i2) { \
        a[i2][0] = *(const int4v*)(fA + (buf) * 32768 + ((mh) * 4 + i2) * 2048 + sw0); \
        a[i2][1] = *(const int4v*)(fA + (buf) * 32768 + ((mh) * 4 + i2) * 2048 + sw1); \
    } \
} while (0)
#define LDB(buf, j0) do { \
    _Pragma("unroll") \
    for (int j2 = 0; j2 < 2; ++j2) { \
        b[(j0) + j2][0] = *(const int4v*)(fB + (buf) * 32768 + ((j0) + j2) * 2048 + sw0); \
        b[(j0) + j2][1] = *(const int4v*)(fB + (buf) * 32768 + ((j0) + j2) * 2048 + sw1); \
    } \
} while (0)
#define MFMAQ(mh, j0) do { \
    _Pragma("unroll") \
    for (int i2 = 0; i2 < 4; ++i2) \
    _Pragma("unroll") \
    for (int j2 = 0; j2 < 2; ++j2) { \
        acc[(mh) * 4 + i2][(j0) + j2] = __builtin_amdgcn_mfma_i32_16x16x64_i8( \
            a[i2][0], b[(j0) + j2][0], acc[(mh) * 4 + i2][(j0) + j2], 0, 0, 0); \
        acc[(mh) * 4 + i2][(j0) + j2] = __builtin_amdgcn_mfma_i32_16x16x64_i8( \
            a[i2][1], b[(j0) + j2][1], acc[(mh) * 4 + i2][(j0) + j2], 0, 0, 0); \
    } \
} while (0)

    // Per-K-tile compute: open-barrier; read b (all j) + a (mh0); 32 MFMA;
    // read a (mh1) -- WAR on a[] lets the reads issue while the mh0 MFMA queue
    // drains; 32 MFMA reusing b; close-barrier. b stays live the whole tile.
#define TILE_COMPUTE(buf) do { \
    __builtin_amdgcn_s_barrier();               /* open: buf staged (vmcnt'd by all) */ \
    LDB(buf, 0); LDA(buf, 0); LDB(buf, 2); \
    __builtin_amdgcn_s_setprio(1); \
    MFMAQ(0, 0); MFMAQ(0, 2); \
    __builtin_amdgcn_s_setprio(0); \
    LDA(buf, 1); \
    __builtin_amdgcn_s_setprio(1); \
    MFMAQ(1, 0); MFMAQ(1, 2); \
    __builtin_amdgcn_s_setprio(0); \
    __builtin_amdgcn_s_barrier();               /* close: all reads of buf retired */ \
} while (0)

    // prologue: tile0 -> buf0 (8 calls; retired by first vmcnt(8)).
    STG_TILE(0, 0);

    // 32 K-tiles of 128; 2 per iteration. Queue invariant at each vmcnt(8):
    // outstanding = {current tile: 8, next tile: 8} -> wait retires exactly the
    // tile being opened; 8 stay in flight (1-tile lead ~2600 cyc >> HBM ~900).
#pragma unroll 1
    for (int it = 0; it < 16; ++it) {
        const int kt = it * 2;
        const bool more = (it < 15);

        // ---- tile kt (buf0) ----
        STG_TILE(1, kt + 1);                       // stage next -> buf1 (closed last iter)
        asm volatile("s_waitcnt vmcnt(8)" ::: "memory");
        TILE_COMPUTE(0);

        // ---- tile kt+1 (buf1) ----
        if (more) {
            STG_TILE(0, kt + 2);                   // stage next-next -> buf0 (just closed)
            asm volatile("s_waitcnt vmcnt(8)" ::: "memory");
        } else {
            asm volatile("s_waitcnt vmcnt(0)" ::: "memory");
        }
        TILE_COMPUTE(1);
    }

    // ---- epilogue: LDS-staged transpose -> coalesced dwordx4 C stores ----
    // lds[] is dead after the final close-barrier. Each wave owns a disjoint 16 KiB
    // region viewed as fp32[64][64], column-XOR-swizzled by ((row&7)<<2):
    //   write side (b32): 2-way bank aliasing = free; read side (b128): bijective.
    // No barriers needed: regions are per-wave; intra-wave ordering via lgkmcnt.
    {
        float* reg4 = (float*)(lds + wave * 16384);
        const int ec = lane & 15;
        const int er = (lane >> 4) << 2;
        const size_t growBase = (size_t)(bm * 256 + waveM);
        const size_t gcolBase = (size_t)(bn * 256 + waveN);
#pragma unroll
        for (int h = 0; h < 2; ++h) {
            // write phase: scaled fp32 into swizzled [64][64]
#pragma unroll
            for (int i2 = 0; i2 < 4; ++i2) {
                const int rbase = i2 * 16 + er;
                const float4 s4 = *(const float4*)(scales + growBase + h * 64 + rbase);
                const float sc4[4] = {s4.x, s4.y, s4.z, s4.w};
#pragma unroll
                for (int j = 0; j < 4; ++j) {
                    const int col = j * 16 + ec;
#pragma unroll
                    for (int rr = 0; rr < 4; ++rr) {
                        const int row = rbase + rr;
                        reg4[row * 64 + (col ^ ((row & 7) << 2))] =
                            (float)acc[h * 4 + i2][j][rr] * sc4[rr];
                    }
                }
            }
            // read phase: per instruction 4 rows x 256B contiguous -> dwordx4 stores
            const int c4 = ec << 2;
#pragma unroll 4
            for (int q = 0; q < 16; ++q) {
                const int R = (lane >> 4) + q * 4;
                const floatx4 v = *(const floatx4*)&reg4[R * 64 + (c4 ^ ((R & 7) << 2))];
                float* dst = C + (growBase + h * 64 + R) * N_DIM + gcolBase + c4;
                __builtin_nontemporal_store(v, (floatx4*)dst);
            }
        }
    }
}

// ---------------- fallback GEMM (no workspace): bf16, inline-converts x and W ----------------
__global__ __launch_bounds__(256) void gemm_fb(const float* __restrict__ X,
                                               const int* __restrict__ W,
                                               float* __restrict__ C) {
    __shared__ __attribute__((aligned(16))) unsigned short sA[128 * 32];
    __shared__ __attribute__((aligned(16))) unsigned short sB[128 * 32];

    const int t    = threadIdx.x;
    const int lane = t & 63;
    const int wave = t >> 6;
    const int bn   = blockIdx.x;
    const int bm   = blockIdx.y;
    const int waveM = (wave >> 1) * 64;
    const int waveN = (wave & 1) * 64;

    const int ar = t >> 1, ac = (t & 1) << 4;
    const float* gX = X + (size_t)(bm * 128 + ar) * K_DIM + ac;
    const int br = t >> 3, bc = (t & 7) << 4;
    const int* gW = W + (size_t)br * N_DIM + bn * 128 + bc;

    const int fr = lane & 15;
    const int fk = (lane >> 4) << 3;
    const unsigned short* fA = sA + (waveM + fr) * 32 + fk;
    const unsigned short* fB = sB + (waveN + fr) * 32 + fk;

    floatx4 acc[4][4];
#pragma unroll
    for (int i = 0; i < 4; ++i)
#pragma unroll
        for (int j = 0; j < 4; ++j) acc[i][j] = (floatx4){0.f, 0.f, 0.f, 0.f};

    for (int k0 = 0; k0 < K_DIM; k0 += 32) {
        {
            const float4* p = (const float4*)gX;
            float4 v0 = p[0], v1 = p[1], v2 = p[2], v3 = p[3];
            uint4 o0, o1;
            o0.x = (unsigned int)f2bf(v0.x) | ((unsigned int)f2bf(v0.y) << 16);
            o0.y = (unsigned int)f2bf(v0.z) | ((unsigned int)f2bf(v0.w) << 16);
            o0.z = (unsigned int)f2bf(v1.x) | ((unsigned int)f2bf(v1.y) << 16);
            o0.w = (unsigned int)f2bf(v1.z) | ((unsigned int)f2bf(v1.w) << 16);
            o1.x = (unsigned int)f2bf(v2.x) | ((unsigned int)f2bf(v2.y) << 16);
            o1.y = (unsigned int)f2bf(v2.z) | ((unsigned int)f2bf(v2.w) << 16);
            o1.z = (unsigned int)f2bf(v3.x) | ((unsigned int)f2bf(v3.y) << 16);
            o1.w = (unsigned int)f2bf(v3.z) | ((unsigned int)f2bf(v3.w) << 16);
            uint4* d = (uint4*)&sA[ar * 32 + ac];
            d[0] = o0; d[1] = o1;
        }
        {
#pragma unroll
            for (int q = 0; q < 4; ++q) {
                int4 v = ((const int4*)gW)[q];
                sB[(bc + q * 4 + 0) * 32 + br] = f2bf((float)v.x);
                sB[(bc + q * 4 + 1) * 32 + br] = f2bf((float)v.y);
                sB[(bc + q * 4 + 2) * 32 + br] = f2bf((float)v.z);
                sB[(bc + q * 4 + 3) * 32 + br] = f2bf((float)v.w);
            }
        }
        gX += 32;
        gW += (size_t)32 * N_DIM;
        __syncthreads();

        short8 a[4], b[4];
#pragma unroll
        for (int i = 0; i < 4; ++i) a[i] = *(const short8*)(fA + i * 16 * 32);
#pragma unroll
        for (int j = 0; j < 4; ++j) b[j] = *(const short8*)(fB + j * 16 * 32);
#pragma unroll
        for (int i = 0; i < 4; ++i)
#pragma unroll
            for (int j = 0; j < 4; ++j)
                acc[i][j] = __builtin_amdgcn_mfma_f32_16x16x32_bf16(a[i], b[j], acc[i][j], 0, 0, 0);
        __syncthreads();
    }

    const int er = (lane >> 4) << 2;
    const int ec = lane & 15;
#pragma unroll
    for (int i = 0; i < 4; ++i)
#pragma unroll
        for (int j = 0; j < 4; ++j) {
            const size_t row0 = (size_t)(bm * 128 + waveM + i * 16 + er);
            const size_t col  = (size_t)(bn * 128 + waveN + j * 16 + ec);
#pragma unroll
            for (int rr = 0; rr < 4; ++rr) C[(row0 + rr) * N_DIM + col] = acc[i][j][rr];
        }
}

extern "C" void kernel_launch(void* const* d_in, const int* in_sizes, int n_in,
                              void* d_out, int out_size, void* d_ws, size_t ws_size,
                              hipStream_t stream) {
    const float* x = (const float*)d_in[0];
    const int*   w = (const int*)d_in[1];
    float* out = (float*)d_out;

    const size_t bytesXq = (size_t)M_DIM * K_DIM;        // 32 MiB
    const size_t bytesWT = (size_t)K_DIM * N_DIM;        // 16 MiB
    const size_t bytesSc = (size_t)M_DIM * sizeof(float);

    if (ws_size >= bytesXq + bytesWT + bytesSc) {
        char*  Xq = (char*)d_ws;
        char*  WT = (char*)d_ws + bytesXq;
        float* Sc = (float*)((char*)d_ws + bytesXq + bytesWT);
        prep_kernel<<<M_DIM + (N_DIM / 64) * (K_DIM / 64), 256, 0, stream>>>(x, w, Xq, Sc, WT);
        gemm_i8<<<dim3(N_DIM / 256, M_DIM / 256), 512, 0, stream>>>(Xq, WT, Sc, out);
    } else {
        gemm_fb<<<dim3(N_DIM / 128, M_DIM / 128), 256, 0, stream>>>(x, w, out);
    }
}

// Round 10
// 378.228 us; speedup vs baseline: 1.1296x; 1.0197x over previous
//
#include <hip/hip_runtime.h>
#include <hip/hip_bf16.h>

// out[8192,4096] fp32 = x[8192,4096] fp32 @ W[4096,4096] (int8 in int32 container)
// Path: fused prep (per-row int8 quantize x || W transpose) -> i8 MFMA GEMM
// (256x256 tile, BK=128, 8-phase counted-vmcnt pipeline, 16x16x64 i8 MFMA,
// XOR-swizzled LDS, XCD-swizzled grid, LDS-staged coalesced dwordx4 epilogue).
// [Round-4 verified state: gemm 135 us, MfmaUtil 44.3, WRITE 131.3 MB, conflicts 0.]
#define M_DIM 8192
#define N_DIM 4096
#define K_DIM 4096

typedef __attribute__((ext_vector_type(4))) int int4v;
typedef __attribute__((ext_vector_type(8))) short short8;
typedef __attribute__((ext_vector_type(4))) float floatx4;

__device__ __forceinline__ unsigned short f2bf(float f) {
    union { float f; unsigned int u; } cv; cv.f = f;
    unsigned int u = cv.u;
    return (unsigned short)((u + 0x7fffu + ((u >> 16) & 1u)) >> 16);
}

// ---------------- fused pre-pass: blocks [0,8192) quantize x rows; [8192,12288) transpose W ----------------
__global__ __launch_bounds__(256) void prep_kernel(const float* __restrict__ X,
                                                   const int* __restrict__ W,
                                                   char* __restrict__ Xq,
                                                   float* __restrict__ scales,
                                                   char* __restrict__ WT) {
    __shared__ float wmax[4];
    __shared__ int trans[64][17];
    const int t = threadIdx.x;

    if (blockIdx.x < M_DIM) {
        // ---- xq: one row per block ----
        const int row = blockIdx.x;
        const float4* src = (const float4*)(X + (size_t)row * K_DIM);
        float4 v[4];
        float am = 0.f;
#pragma unroll
        for (int i = 0; i < 4; ++i) {
            v[i] = src[t + i * 256];
            am = fmaxf(am, fmaxf(fmaxf(fabsf(v[i].x), fabsf(v[i].y)),
                                 fmaxf(fabsf(v[i].z), fabsf(v[i].w))));
        }
#pragma unroll
        for (int off = 32; off; off >>= 1) am = fmaxf(am, __shfl_xor(am, off, 64));
        if ((t & 63) == 0) wmax[t >> 6] = am;
        __syncthreads();
        am = fmaxf(fmaxf(wmax[0], wmax[1]), fmaxf(wmax[2], wmax[3]));
        am = fmaxf(am, 1e-20f);
        const float inv = 127.f / am;
        unsigned int* dst = (unsigned int*)(Xq + (size_t)row * K_DIM);
#pragma unroll
        for (int i = 0; i < 4; ++i) {
            int q0 = __float2int_rn(v[i].x * inv);
            int q1 = __float2int_rn(v[i].y * inv);
            int q2 = __float2int_rn(v[i].z * inv);
            int q3 = __float2int_rn(v[i].w * inv);
            dst[t + i * 256] = (unsigned int)(q0 & 255) | ((unsigned int)(q1 & 255) << 8) |
                               ((unsigned int)(q2 & 255) << 16) | ((unsigned int)q3 << 24);
        }
        if (t == 0) scales[row] = am * (1.f / 127.f);
    } else {
        // ---- wq: 64x64 tile transpose, W[K][N] int32 -> WT[N][K] int8 ----
        const int b  = blockIdx.x - M_DIM;
        const int tn = b & 63;          // N/64 = 64
        const int tk = b >> 6;          // K/64 = 64
        const int n  = t & 63;
        const int kg = t >> 6;

#pragma unroll
        for (int p = 0; p < 4; ++p) {
            const int kb = p * 16 + kg * 4;
            const int* src = W + (size_t)(tk * 64 + kb) * N_DIM + tn * 64 + n;
            int v0 = src[0];
            int v1 = src[N_DIM];
            int v2 = src[2 * N_DIM];
            int v3 = src[3 * N_DIM];
            trans[n][kb >> 2] = (v0 & 255) | ((v1 & 255) << 8) | ((v2 & 255) << 16) |
                                ((unsigned int)v3 << 24);
        }
        __syncthreads();

        const int n2 = t >> 2;
        const int c  = t & 3;
        int o0 = trans[n2][c * 4 + 0];
        int o1 = trans[n2][c * 4 + 1];
        int o2 = trans[n2][c * 4 + 2];
        int o3 = trans[n2][c * 4 + 3];
        char* dst = WT + (size_t)(tn * 64 + n2) * K_DIM + tk * 64 + c * 16;
        int4 o; o.x = o0; o.y = o1; o.z = o2; o.w = o3;
        *(int4*)dst = o;
    }
}

// ---------------- main GEMM: 256x256 tile, BK=128, 8 waves, 8-phase pipeline ----------------
// LDS: A [2][256][128] at 0 (64 KiB), B [2][256][128] at 65536 (64 KiB).
// Swizzle: 16B chunk slot s stores global chunk c = s ^ (row & 7) (involution).
// global_load_lds dest is linear (wave base + lane*16); source address carries the swizzle.
#define GLL(src, dst) __builtin_amdgcn_global_load_lds( \
    (const __attribute__((address_space(1))) void*)(src), \
    (__attribute__((address_space(3))) void*)(dst), 16, 0, 0)

__global__ __launch_bounds__(512, 2) void gemm_i8(const char* __restrict__ A,
                                                  const char* __restrict__ BT,
                                                  const float* __restrict__ scales,
                                                  float* __restrict__ C) {
    __shared__ __attribute__((aligned(16))) char lds[131072];

    const int t    = threadIdx.x;
    const int lane = t & 63;
    const int wave = t >> 6;

    // XCD-aware chunked swizzle (bijective: 512 tiles, 512 % 8 == 0, 64 per XCD).
    const int lin = blockIdx.y * 16 + blockIdx.x;      // grid = (16, 32)
    const int wg  = ((lin & 7) << 6) + (lin >> 3);
    const int bn  = wg & 15;
    const int bm  = wg >> 4;

    const int waveM = (wave >> 2) * 128;   // 2 M-groups
    const int waveN = (wave & 3) * 64;     // 4 N-groups

    // staging: thread t -> row = t>>3 within a 64-row call, chunk slot = t&7.
    // Pre-swizzled source chunk so linear LDS write lands swizzled.
    const int srow = t >> 3;                     // 0..63
    const int schk = (t & 7) ^ (srow & 7);
    const char* aSrc = A  + (size_t)(bm * 256 + srow) * K_DIM + schk * 16;
    const char* bSrc = BT + (size_t)(bn * 256 + srow) * K_DIM + schk * 16;
    char* aDst = lds + wave * 1024;              // wave-uniform; HW adds lane*16
    char* bDst = lds + 65536 + wave * 1024;

#define STG_A(buf, r0, kt) do { \
    GLL(aSrc + (size_t)(r0) * K_DIM + (kt) * 128,        aDst + (buf) * 32768 + (r0) * 128); \
    GLL(aSrc + (size_t)((r0) + 64) * K_DIM + (kt) * 128, aDst + (buf) * 32768 + ((r0) + 64) * 128); \
} while (0)
#define STG_B(buf, r0, kt) do { \
    GLL(bSrc + (size_t)(r0) * K_DIM + (kt) * 128,        bDst + (buf) * 32768 + (r0) * 128); \
    GLL(bSrc + (size_t)((r0) + 64) * K_DIM + (kt) * 128, bDst + (buf) * 32768 + ((r0) + 64) * 128); \
} while (0)

    // fragment reads: row = waveBase + frag*16 + (lane&15), chunk = kk*4 + (lane>>4),
    // swizzled slot = chunk ^ (row&7) = chunk ^ (lane&7).
    const char* fA = lds + (waveM + (lane & 15)) * 128;
    const char* fB = lds + 65536 + (waveN + (lane & 15)) * 128;
    const int sw0 = (((lane >> 4) + 0) ^ (lane & 7)) * 16;   // kk = 0
    const int sw1 = (((lane >> 4) + 4) ^ (lane & 7)) * 16;   // kk = 1

    int4v acc[8][4];
#pragma unroll
    for (int i = 0; i < 8; ++i)
#pragma unroll
        for (int j = 0; j < 4; ++j) acc[i][j] = (int4v){0, 0, 0, 0};

    int4v a[4][2], b[4][2];

#define LDA(buf, mh) do { \
    _Pragma("unroll") \
    for (int i2 = 0; i2 < 4; ++i2) { \
        a[i2][0] = *(const int4v*)(fA + (buf) * 32768 + ((mh) * 4 + i2) * 2048 + sw0); \
        a[i2][1] = *(const int4v*)(fA + (buf) * 32768 + ((mh) * 4 + i2) * 2048 + sw1); \
    } \
} while (0)
#define LDB(buf, j0) do { \
    _Pragma("unroll") \
    for (int j2 = 0; j2 < 2; ++j2) { \
        b[(j0) + j2][0] = *(const int4v*)(fB + (buf) * 32768 + ((j0) + j2) * 2048 + sw0); \
        b[(j0) + j2][1] = *(const int4v*)(fB + (buf) * 32768 + ((j0) + j2) * 2048 + sw1); \
    } \
} while (0)
#define MFMAQ(mh, j0) do { \
    _Pragma("unroll") \
    for (int i2 = 0; i2 < 4; ++i2) \
    _Pragma("unroll") \
    for (int j2 = 0; j2 < 2; ++j2) { \
        acc[(mh) * 4 + i2][(j0) + j2] = __builtin_amdgcn_mfma_i32_16x16x64_i8( \
            a[i2][0], b[(j0) + j2][0], acc[(mh) * 4 + i2][(j0) + j2], 0, 0, 0); \
        acc[(mh) * 4 + i2][(j0) + j2] = __builtin_amdgcn_mfma_i32_16x16x64_i8( \
            a[i2][1], b[(j0) + j2][1], acc[(mh) * 4 + i2][(j0) + j2], 0, 0, 0); \
    } \
} while (0)

    // prologue: tile0 (A+B) -> buf0 (8 calls, drained at first vmcnt(6)),
    // then tile1 B -> buf1 (4 calls, stay in flight).
    STG_A(0, 0, 0); STG_A(0, 128, 0);
    STG_B(0, 0, 0); STG_B(0, 128, 0);
    STG_B(1, 0, 1); STG_B(1, 128, 1);

    // 32 K-tiles of 128; 2 tiles per iteration (buf0 then buf1), 8 phases.
#pragma unroll 1
    for (int it = 0; it < 16; ++it) {
        const int kt = it * 2;
        const bool more = (it < 15);

        // ---- phase 0: tile-start buf0 (tile kt), quadrant (mh=0, j=0..1) ----
        STG_A(1, 0, kt + 1);
        asm volatile("s_waitcnt vmcnt(6)" ::: "memory");
        __builtin_amdgcn_s_barrier();
        LDA(0, 0); LDB(0, 0);
        __builtin_amdgcn_s_setprio(1);
        MFMAQ(0, 0);
        __builtin_amdgcn_s_setprio(0);
        __builtin_amdgcn_s_barrier();

        // ---- phase 1: quadrant (0, j=2..3) ----
        STG_A(1, 128, kt + 1);
        LDB(0, 2);
        __builtin_amdgcn_s_barrier();
        __builtin_amdgcn_s_setprio(1);
        MFMAQ(0, 2);
        __builtin_amdgcn_s_setprio(0);
        __builtin_amdgcn_s_barrier();

        // ---- phase 2: quadrant (1, j=2..3) ----
        if (more) STG_B(0, 0, kt + 2);
        LDA(0, 1);
        __builtin_amdgcn_s_barrier();
        __builtin_amdgcn_s_setprio(1);
        MFMAQ(1, 2);
        __builtin_amdgcn_s_setprio(0);
        __builtin_amdgcn_s_barrier();

        // ---- phase 3: quadrant (1, j=0..1), frags cached ----
        if (more) STG_B(0, 128, kt + 2);
        __builtin_amdgcn_s_barrier();
        __builtin_amdgcn_s_setprio(1);
        MFMAQ(1, 0);
        __builtin_amdgcn_s_setprio(0);
        __builtin_amdgcn_s_barrier();

        // ---- phase 4: tile-start buf1 (tile kt+1), quadrant (0, 0..1) ----
        if (more) {
            STG_A(0, 0, kt + 2);
            asm volatile("s_waitcnt vmcnt(6)" ::: "memory");
        } else {
            asm volatile("s_waitcnt vmcnt(0)" ::: "memory");
        }
        __builtin_amdgcn_s_barrier();
        LDA(1, 0); LDB(1, 0);
        __builtin_amdgcn_s_setprio(1);
        MFMAQ(0, 0);
        __builtin_amdgcn_s_setprio(0);
        __builtin_amdgcn_s_barrier();

        // ---- phase 5 ----
        if (more) STG_A(0, 128, kt + 2);
        LDB(1, 2);
        __builtin_amdgcn_s_barrier();
        __builtin_amdgcn_s_setprio(1);
        MFMAQ(0, 2);
        __builtin_amdgcn_s_setprio(0);
        __builtin_amdgcn_s_barrier();

        // ---- phase 6 ----
        if (more) STG_B(1, 0, kt + 3);
        LDA(1, 1);
        __builtin_amdgcn_s_barrier();
        __builtin_amdgcn_s_setprio(1);
        MFMAQ(1, 2);
        __builtin_amdgcn_s_setprio(0);
        __builtin_amdgcn_s_barrier();

        // ---- phase 7 ----
        if (more) STG_B(1, 128, kt + 3);
        __builtin_amdgcn_s_barrier();
        __builtin_amdgcn_s_setprio(1);
        MFMAQ(1, 0);
        __builtin_amdgcn_s_setprio(0);
        __builtin_amdgcn_s_barrier();
    }

    // ---- epilogue: LDS-staged transpose -> coalesced dwordx4 C stores ----
    // lds[] is dead after the final barrier. Each wave owns a disjoint 16 KiB region
    // viewed as fp32[64][64], column-XOR-swizzled by ((row&7)<<2):
    //   write side (b32): 2-way bank aliasing = free; read side (b128): bijective.
    // No barriers needed: regions are per-wave; intra-wave ordering via lgkmcnt.
    {
        float* reg4 = (float*)(lds + wave * 16384);
        const int ec = lane & 15;
        const int er = (lane >> 4) << 2;
        const size_t growBase = (size_t)(bm * 256 + waveM);
        const size_t gcolBase = (size_t)(bn * 256 + waveN);
#pragma unroll
        for (int h = 0; h < 2; ++h) {
            // write phase: scaled fp32 into swizzled [64][64]
#pragma unroll
            for (int i2 = 0; i2 < 4; ++i2) {
                const int rbase = i2 * 16 + er;
                const float4 s4 = *(const float4*)(scales + growBase + h * 64 + rbase);
                const float sc4[4] = {s4.x, s4.y, s4.z, s4.w};
#pragma unroll
                for (int j = 0; j < 4; ++j) {
                    const int col = j * 16 + ec;
#pragma unroll
                    for (int rr = 0; rr < 4; ++rr) {
                        const int row = rbase + rr;
                        reg4[row * 64 + (col ^ ((row & 7) << 2))] =
                            (float)acc[h * 4 + i2][j][rr] * sc4[rr];
                    }
                }
            }
            // read phase: per instruction 4 rows x 256B contiguous -> dwordx4 stores
            const int c4 = ec << 2;
#pragma unroll 4
            for (int q = 0; q < 16; ++q) {
                const int R = (lane >> 4) + q * 4;
                const floatx4 v = *(const floatx4*)&reg4[R * 64 + (c4 ^ ((R & 7) << 2))];
                float* dst = C + (growBase + h * 64 + R) * N_DIM + gcolBase + c4;
                __builtin_nontemporal_store(v, (floatx4*)dst);
            }
        }
    }
}

// ---------------- fallback GEMM (no workspace): bf16, inline-converts x and W ----------------
__global__ __launch_bounds__(256) void gemm_fb(const float* __restrict__ X,
                                               const int* __restrict__ W,
                                               float* __restrict__ C) {
    __shared__ __attribute__((aligned(16))) unsigned short sA[128 * 32];
    __shared__ __attribute__((aligned(16))) unsigned short sB[128 * 32];

    const int t    = threadIdx.x;
    const int lane = t & 63;
    const int wave = t >> 6;
    const int bn   = blockIdx.x;
    const int bm   = blockIdx.y;
    const int waveM = (wave >> 1) * 64;
    const int waveN = (wave & 1) * 64;

    const int ar = t >> 1, ac = (t & 1) << 4;
    const float* gX = X + (size_t)(bm * 128 + ar) * K_DIM + ac;
    const int br = t >> 3, bc = (t & 7) << 4;
    const int* gW = W + (size_t)br * N_DIM + bn * 128 + bc;

    const int fr = lane & 15;
    const int fk = (lane >> 4) << 3;
    const unsigned short* fA = sA + (waveM + fr) * 32 + fk;
    const unsigned short* fB = sB + (waveN + fr) * 32 + fk;

    floatx4 acc[4][4];
#pragma unroll
    for (int i = 0; i < 4; ++i)
#pragma unroll
        for (int j = 0; j < 4; ++j) acc[i][j] = (floatx4){0.f, 0.f, 0.f, 0.f};

    for (int k0 = 0; k0 < K_DIM; k0 += 32) {
        {
            const float4* p = (const float4*)gX;
            float4 v0 = p[0], v1 = p[1], v2 = p[2], v3 = p[3];
            uint4 o0, o1;
            o0.x = (unsigned int)f2bf(v0.x) | ((unsigned int)f2bf(v0.y) << 16);
            o0.y = (unsigned int)f2bf(v0.z) | ((unsigned int)f2bf(v0.w) << 16);
            o0.z = (unsigned int)f2bf(v1.x) | ((unsigned int)f2bf(v1.y) << 16);
            o0.w = (unsigned int)f2bf(v1.z) | ((unsigned int)f2bf(v1.w) << 16);
            o1.x = (unsigned int)f2bf(v2.x) | ((unsigned int)f2bf(v2.y) << 16);
            o1.y = (unsigned int)f2bf(v2.z) | ((unsigned int)f2bf(v2.w) << 16);
            o1.z = (unsigned int)f2bf(v3.x) | ((unsigned int)f2bf(v3.y) << 16);
            o1.w = (unsigned int)f2bf(v3.z) | ((unsigned int)f2bf(v3.w) << 16);
            uint4* d = (uint4*)&sA[ar * 32 + ac];
            d[0] = o0; d[1] = o1;
        }
        {
#pragma unroll
            for (int q = 0; q < 4; ++q) {
                int4 v = ((const int4*)gW)[q];
                sB[(bc + q * 4 + 0) * 32 + br] = f2bf((float)v.x);
                sB[(bc + q * 4 + 1) * 32 + br] = f2bf((float)v.y);
                sB[(bc + q * 4 + 2) * 32 + br] = f2bf((float)v.z);
                sB[(bc + q * 4 + 3) * 32 + br] = f2bf((float)v.w);
            }
        }
        gX += 32;
        gW += (size_t)32 * N_DIM;
        __syncthreads();

        short8 a[4], b[4];
#pragma unroll
        for (int i = 0; i < 4; ++i) a[i] = *(const short8*)(fA + i * 16 * 32);
#pragma unroll
        for (int j = 0; j < 4; ++j) b[j] = *(const short8*)(fB + j * 16 * 32);
#pragma unroll
        for (int i = 0; i < 4; ++i)
#pragma unroll
            for (int j = 0; j < 4; ++j)
                acc[i][j] = __builtin_amdgcn_mfma_f32_16x16x32_bf16(a[i], b[j], acc[i][j], 0, 0, 0);
        __syncthreads();
    }

    const int er = (lane >> 4) << 2;
    const int ec = lane & 15;
#pragma unroll
    for (int i = 0; i < 4; ++i)
#pragma unroll
        for (int j = 0; j < 4; ++j) {
            const size_t row0 = (size_t)(bm * 128 + waveM + i * 16 + er);
            const size_t col  = (size_t)(bn * 128 + waveN + j * 16 + ec);
#pragma unroll
            for (int rr = 0; rr < 4; ++rr) C[(row0 + rr) * N_DIM + col] = acc[i][j][rr];
        }
}

extern "C" void kernel_launch(void* const* d_in, const int* in_sizes, int n_in,
                              void* d_out, int out_size, void* d_ws, size_t ws_size,
                              hipStream_t stream) {
    const float* x = (const float*)d_in[0];
    const int*   w = (const int*)d_in[1];
    float* out = (float*)d_out;

    const size_t bytesXq = (size_t)M_DIM * K_DIM;        // 32 MiB
    const size_t bytesWT = (size_t)K_DIM * N_DIM;        // 16 MiB
    const size_t bytesSc = (size_t)M_DIM * sizeof(float);

    if (ws_size >= bytesXq + bytesWT + bytesSc) {
        char*  Xq = (char*)d_ws;
        char*  WT = (char*)d_ws + bytesXq;
        float* Sc = (float*)((char*)d_ws + bytesXq + bytesWT);
        prep_kernel<<<M_DIM + (N_DIM / 64) * (K_DIM / 64), 256, 0, stream>>>(x, w, Xq, Sc, WT);
        gemm_i8<<<dim3(N_DIM / 256, M_DIM / 256), 512, 0, stream>>>(Xq, WT, Sc, out);
    } else {
        gemm_fb<<<dim3(N_DIM / 128, M_DIM / 128), 256, 0, stream>>>(x, w, out);
    }
}